// Round 1
// baseline (889.873 us; speedup 1.0000x reference)
//
#include <hip/hip_runtime.h>

#define NSP 4

typedef unsigned short u16;
typedef __bf16 v8bf __attribute__((ext_vector_type(8)));
typedef float v4f __attribute__((ext_vector_type(4)));

__device__ __forceinline__ u16 f2bf(float f){
  union { float f; unsigned u; } v; v.f = f;
  unsigned u = v.u;
  u += 0x7fffu + ((u >> 16) & 1u);   // round-to-nearest-even
  return (u16)(u >> 16);
}

__device__ __forceinline__ float fast_tanh(float x){
  float xc = fminf(fmaxf(x, -9.f), 9.f);       // avoid inf/inf
  float e = __expf(2.f * xc);
  return (e - 1.f) * __builtin_amdgcn_rcpf(e + 1.f);
}

// ---------------- sorting pipeline ----------------

__global__ void init_k(int* __restrict__ counts2){
  counts2[threadIdx.x] = 0;   // 256 shadow counters [s*64+b]
}

__global__ void hist_k(const int* __restrict__ sp, int n, int* __restrict__ counts2){
  int i = blockIdx.x * 256 + threadIdx.x;
  int sv = (i < n) ? sp[i] : -1;
  int b = blockIdx.x & 63;
  int lane = threadIdx.x & 63;
  #pragma unroll
  for (int s = 0; s < NSP; ++s){
    unsigned long long m = __ballot(sv == s);
    if (lane == 0 && m) atomicAdd(&counts2[s*64 + b], (int)__popcll(m));
  }
}

__global__ void scan_k(const int* __restrict__ counts2, int* __restrict__ cursors2,
                       int* __restrict__ segOff){
  int run = 0;
  for (int s = 0; s < NSP; ++s){
    segOff[s] = run;
    for (int b = 0; b < 64; ++b){
      cursors2[s*64 + b] = run;
      run += counts2[s*64 + b];
    }
  }
  segOff[NSP] = run;
}

__global__ void scatter_k(const int* __restrict__ sp, int n,
                          int* __restrict__ cursors2, int* __restrict__ sorted){
  int i = blockIdx.x * 256 + threadIdx.x;
  int sv = (i < n) ? sp[i] : -1;
  int b = blockIdx.x & 63;
  int lane = threadIdx.x & 63;
  #pragma unroll
  for (int s = 0; s < NSP; ++s){
    unsigned long long m = __ballot(sv == s);
    if (!m) continue;
    int leader = __ffsll(m) - 1;
    int base = 0;
    if (lane == leader) base = atomicAdd(&cursors2[s*64 + b], (int)__popcll(m));
    base = __shfl(base, leader, 64);
    if (sv == s){
      int rank = (int)__popcll(m & ((1ull << lane) - 1ull));
      sorted[base + rank] = i;
    }
  }
}

// convert W1,W2 to bf16 transposed (n-major) layouts: W1T[s][n][k], W2T[s][n][k]
__global__ void wconv_k(const float* __restrict__ W1, const float* __restrict__ W2,
                        u16* __restrict__ w1t, u16* __restrict__ w2t){
  int i = blockIdx.x * 256 + threadIdx.x;
  if (i < NSP*128*64){
    int s = i >> 13, rem = i & 8191, k = rem >> 6, nn = rem & 63;
    w1t[(s*64 + nn)*128 + k] = f2bf(W1[i]);
  }
  if (i < NSP*64*64){
    int s = i >> 12, rem = i & 4095, k = rem >> 6, nn = rem & 63;
    w2t[(s*64 + nn)*64 + k] = f2bf(W2[i]);
  }
}

// ---------------- main MLP kernel ----------------
// 64-atom tile per block, one species per block.
// LDS: sA holds features [64][136 pad] bf16, then overlaid h1 [64][72 pad].
//      sB holds W1T [64][136], then overlaid W2T [64][72].

__global__ __launch_bounds__(256, 4) void mlp_k(
    const float* __restrict__ feats,
    const float* __restrict__ b1, const float* __restrict__ b2,
    const float* __restrict__ W3, const float* __restrict__ b3,
    const int* __restrict__ segOff, const int* __restrict__ sorted,
    const u16* __restrict__ w1t, const u16* __restrict__ w2t,
    float* __restrict__ out)
{
  __shared__ u16 sA[64*136];
  __shared__ u16 sB[64*136];
  __shared__ int sIdx[64];
  __shared__ float sB1[64], sB2[64], sW3[64];

  int o0=segOff[0], o1=segOff[1], o2=segOff[2], o3=segOff[3], o4=segOff[4];
  int offs[5] = {o0,o1,o2,o3,o4};
  int t = blockIdx.x;
  int s = 0, segBase = 0, segCnt = 0;
  bool found = false;
  #pragma unroll
  for (int ss = 0; ss < NSP; ++ss){
    int cs = offs[ss+1] - offs[ss];
    int tl = (cs + 63) >> 6;
    if (!found){
      if (t < tl){ s = ss; segBase = offs[ss]; segCnt = cs; found = true; }
      else t -= tl;
    }
  }
  if (!found) return;
  int m0 = t << 6;
  int tid = threadIdx.x;

  if (tid < 64){
    int gm = m0 + tid; int gc = segCnt - 1; if (gm > gc) gm = gc;  // clamp tail
    sIdx[tid] = sorted[segBase + gm];
  } else if (tid < 128){
    int j = tid - 64;  sB1[j] = b1[s*64 + j];
  } else if (tid < 192){
    int j = tid - 128; sB2[j] = b2[s*64 + j];
  } else {
    int j = tid - 192; sW3[j] = W3[s*64 + j];
  }
  // W1T -> sB (no dependency on sIdx)
  {
    int r = tid >> 2, q = tid & 3, cb = q*32;
    const uint4* src = (const uint4*)(w1t + (size_t)(s*64 + r)*128 + cb);
    uint4 v0 = src[0], v1 = src[1], v2 = src[2], v3 = src[3];
    uint4* dst = (uint4*)(sA ? (sB + r*136 + cb) : 0);
    dst[0]=v0; dst[1]=v1; dst[2]=v2; dst[3]=v3;
  }
  __syncthreads();
  // gather feature rows -> sA (fp32 -> bf16)
  {
    int r = tid >> 2, q = tid & 3, cb = q*32;
    const float4* src = (const float4*)(feats + (size_t)sIdx[r]*128 + cb);
    u16* dst = sA + r*136 + cb;
    #pragma unroll
    for (int i2 = 0; i2 < 8; ++i2){
      float4 f = src[i2];
      uint2 pk;
      pk.x = (unsigned)f2bf(f.x) | ((unsigned)f2bf(f.y) << 16);
      pk.y = (unsigned)f2bf(f.z) | ((unsigned)f2bf(f.w) << 16);
      *(uint2*)(dst + i2*4) = pk;
    }
  }
  __syncthreads();

  int lane = tid & 63, wv = tid >> 6;
  int cc = lane & 15, quad = lane >> 4;

  // ---- layer 1: [64x128] x [128x64] ----
  v4f acc[4];
  #pragma unroll
  for (int nt = 0; nt < 4; ++nt) acc[nt] = (v4f){0.f,0.f,0.f,0.f};
  const u16* aRow = sA + (wv*16 + cc)*136;
  #pragma unroll
  for (int kk = 0; kk < 4; ++kk){
    v8bf af = *(const v8bf*)(aRow + kk*32 + quad*8);
    #pragma unroll
    for (int nt = 0; nt < 4; ++nt){
      v8bf bfr = *(const v8bf*)(sB + (nt*16 + cc)*136 + kk*32 + quad*8);
      acc[nt] = __builtin_amdgcn_mfma_f32_16x16x32_bf16(af, bfr, acc[nt], 0, 0, 0);
    }
  }
  __syncthreads();   // all reads of sA/sB done; safe to overlay

  // prefetch W2T into regs (hide latency under tanh)
  uint4 w2a, w2b;
  {
    int r = tid >> 2, q = tid & 3, cb = q*16;
    const uint4* src = (const uint4*)(w2t + (size_t)(s*64 + r)*64 + cb);
    w2a = src[0]; w2b = src[1];
  }
  // h1 = tanh(acc + b1) -> sA overlay (stride 72)
  #pragma unroll
  for (int nt = 0; nt < 4; ++nt){
    int j = nt*16 + cc;
    float bj = sB1[j];
    #pragma unroll
    for (int r = 0; r < 4; ++r){
      int m = wv*16 + quad*4 + r;
      sA[m*72 + j] = f2bf(fast_tanh(acc[nt][r] + bj));
    }
  }
  // W2T -> sB overlay (stride 72)
  {
    int r = tid >> 2, q = tid & 3, cb = q*16;
    uint4* dst = (uint4*)(sB + r*72 + cb);
    dst[0] = w2a; dst[1] = w2b;
  }
  __syncthreads();

  // ---- layer 2: [64x64] x [64x64] ----
  v4f acc2[4];
  #pragma unroll
  for (int nt = 0; nt < 4; ++nt) acc2[nt] = (v4f){0.f,0.f,0.f,0.f};
  const u16* hRow = sA + (wv*16 + cc)*72;
  #pragma unroll
  for (int kk = 0; kk < 2; ++kk){
    v8bf af = *(const v8bf*)(hRow + kk*32 + quad*8);
    #pragma unroll
    for (int nt = 0; nt < 4; ++nt){
      v8bf bfr = *(const v8bf*)(sB + (nt*16 + cc)*72 + kk*32 + quad*8);
      acc2[nt] = __builtin_amdgcn_mfma_f32_16x16x32_bf16(af, bfr, acc2[nt], 0, 0, 0);
    }
  }

  // ---- layer 3: fp32 dot with W3, reduce across the 16 cols ----
  float p[4] = {0.f, 0.f, 0.f, 0.f};
  #pragma unroll
  for (int nt = 0; nt < 4; ++nt){
    int j = nt*16 + cc;
    float bj = sB2[j], wj = sW3[j];
    #pragma unroll
    for (int r = 0; r < 4; ++r)
      p[r] += fast_tanh(acc2[nt][r] + bj) * wj;
  }
  #pragma unroll
  for (int off = 8; off >= 1; off >>= 1){
    #pragma unroll
    for (int r = 0; r < 4; ++r) p[r] += __shfl_xor(p[r], off, 64);
  }
  if (cc == 0){
    float b3v = b3[s];
    #pragma unroll
    for (int r = 0; r < 4; ++r){
      int m = wv*16 + quad*4 + r;
      if (m0 + m < segCnt) out[sIdx[m]] = p[r] + b3v;
    }
  }
}

extern "C" void kernel_launch(void* const* d_in, const int* in_sizes, int n_in,
                              void* d_out, int out_size, void* d_ws, size_t ws_size,
                              hipStream_t stream){
  const float* feats  = (const float*)d_in[0];
  const int*   species= (const int*)d_in[1];
  const float* W1 = (const float*)d_in[2];
  const float* b1 = (const float*)d_in[3];
  const float* W2 = (const float*)d_in[4];
  const float* b2 = (const float*)d_in[5];
  const float* W3 = (const float*)d_in[6];
  const float* b3 = (const float*)d_in[7];
  float* out = (float*)d_out;
  int n = in_sizes[1];

  char* ws = (char*)d_ws;
  int* counts2  = (int*)ws;              // 256 ints
  int* cursors2 = (int*)(ws + 1024);     // 256 ints
  int* segOff   = (int*)(ws + 2048);     // 5 ints
  int* sorted   = (int*)(ws + 4096);     // n ints
  size_t sortedBytes = ((size_t)n*4 + 15) & ~(size_t)15;
  u16* w1t = (u16*)(ws + 4096 + sortedBytes);   // 4*64*128 bf16
  u16* w2t = w1t + NSP*64*128;                  // 4*64*64 bf16

  int nb = (n + 255) / 256;
  init_k<<<1, 256, 0, stream>>>(counts2);
  hist_k<<<nb, 256, 0, stream>>>(species, n, counts2);
  wconv_k<<<(NSP*128*64 + 255)/256, 256, 0, stream>>>(W1, W2, w1t, w2t);
  scan_k<<<1, 1, 0, stream>>>(counts2, cursors2, segOff);
  scatter_k<<<nb, 256, 0, stream>>>(species, n, cursors2, sorted);
  int tiles = (n + 63) / 64 + NSP - 1;
  mlp_k<<<tiles, 256, 0, stream>>>(feats, b1, b2, W3, b3, segOff, sorted, w1t, w2t, out);
}

// Round 3
// 872.177 us; speedup vs baseline: 1.0203x; 1.0203x over previous
//
#include <hip/hip_runtime.h>

#define NSP 4

typedef unsigned short u16;
typedef __bf16 v8bf __attribute__((ext_vector_type(8)));
typedef float v4f __attribute__((ext_vector_type(4)));

__device__ __forceinline__ u16 f2bf(float f){           // RNE
  union { float f; unsigned u; } v; v.f = f;
  unsigned u = v.u;
  u += 0x7fffu + ((u >> 16) & 1u);
  return (u16)(u >> 16);
}
__device__ __forceinline__ u16 h2bf(float f){           // round-half-up: 2 VALU ops
  union { float f; unsigned u; } v; v.f = f;
  return (u16)((v.u + 0x8000u) >> 16);
}
__device__ __forceinline__ unsigned pack2bf(float x, float y){
  union { float f; unsigned u; } a, b; a.f = x; b.f = y;
  unsigned ux = a.u + 0x8000u, uy = b.u + 0x8000u;
  return (uy & 0xffff0000u) | (ux >> 16);
}
__device__ __forceinline__ float fast_tanh(float x){
  float xc = fminf(fmaxf(x, -9.f), 9.f);
  float e = __expf(2.f * xc);
  return 1.f - 2.f * __builtin_amdgcn_rcpf(e + 1.f);
}

// ---------------- sorting pipeline ----------------

__global__ void init_k(int* __restrict__ counts2){
  counts2[threadIdx.x] = 0;   // 256 shadow counters [s*64+b]
}

__global__ void hist_k(const int* __restrict__ sp, int n, int* __restrict__ counts2){
  int i = blockIdx.x * 256 + threadIdx.x;
  int sv = (i < n) ? sp[i] : -1;
  int b = blockIdx.x & 63;
  int lane = threadIdx.x & 63;
  #pragma unroll
  for (int s = 0; s < NSP; ++s){
    unsigned long long m = __ballot(sv == s);
    if (lane == 0 && m) atomicAdd(&counts2[s*64 + b], (int)__popcll(m));
  }
}

// parallel exclusive scan over the 256 counters
__global__ void scan_k(const int* __restrict__ counts2, int* __restrict__ cursors2,
                       int* __restrict__ segOff){
  __shared__ int tmp[256];
  int tid = threadIdx.x;
  int v = counts2[tid];
  tmp[tid] = v; __syncthreads();
  #pragma unroll
  for (int off = 1; off < 256; off <<= 1){
    int t = (tid >= off) ? tmp[tid - off] : 0;
    __syncthreads();
    tmp[tid] += t;
    __syncthreads();
  }
  int incl = tmp[tid];
  cursors2[tid] = incl - v;
  if ((tid & 63) == 0) segOff[tid >> 6] = incl - v;
  if (tid == 255)      segOff[NSP] = incl;
}

__global__ void scatter_k(const int* __restrict__ sp, int n,
                          int* __restrict__ cursors2, int* __restrict__ sorted){
  int i = blockIdx.x * 256 + threadIdx.x;
  int sv = (i < n) ? sp[i] : -1;
  int b = blockIdx.x & 63;
  int lane = threadIdx.x & 63;
  #pragma unroll
  for (int s = 0; s < NSP; ++s){
    unsigned long long m = __ballot(sv == s);
    if (!m) continue;
    int leader = __ffsll(m) - 1;
    int base = 0;
    if (lane == leader) base = atomicAdd(&cursors2[s*64 + b], (int)__popcll(m));
    base = __shfl(base, leader, 64);
    if (sv == s){
      int rank = (int)__popcll(m & ((1ull << lane) - 1ull));
      sorted[base + rank] = i;
    }
  }
}

// W1,W2 -> bf16 transposed (n-major): W1T[s][n][k], W2T[s][n][k]
__global__ void wconv_k(const float* __restrict__ W1, const float* __restrict__ W2,
                        u16* __restrict__ w1t, u16* __restrict__ w2t){
  int i = blockIdx.x * 256 + threadIdx.x;
  if (i < NSP*128*64){
    int s = i >> 13, rem = i & 8191, k = rem >> 6, nn = rem & 63;
    w1t[(s*64 + nn)*128 + k] = f2bf(W1[i]);
  }
  if (i < NSP*64*64){
    int s = i >> 12, rem = i & 4095, k = rem >> 6, nn = rem & 63;
    w2t[(s*64 + nn)*64 + k] = f2bf(W2[i]);
  }
}

// ---------------- main MLP kernel ----------------
// One species per block (grid = 4 species x 128 blocks). All weight B-frags
// hoisted to VGPRs; barrier-free grid-stride tile loop; features load
// global->reg A-frags (2-deep software pipeline); h1 round-trips through
// per-wave-private LDS (intra-wave dep only, no __syncthreads).

#define BPS 128   // blocks per species

__global__ __launch_bounds__(256, 2) void mlp2_k(
    const float* __restrict__ feats,
    const float* __restrict__ b1, const float* __restrict__ b2,
    const float* __restrict__ W3, const float* __restrict__ b3,
    const int* __restrict__ segOff, const int* __restrict__ sorted,
    const u16* __restrict__ w1t, const u16* __restrict__ w2t,
    float* __restrict__ out)
{
  __shared__ __align__(16) u16 sW1[64*136];        // 17,408 B
  __shared__ __align__(16) u16 sW2[64*72];         //  9,216 B
  __shared__ float sB1[64], sB2[64], sW3s[64];
  __shared__ __align__(16) u16 sH[4][16*72];       //  9,216 B (per-wave h1 scratch)

  int s  = blockIdx.x >> 7;
  int bs = blockIdx.x & (BPS-1);
  int tid = threadIdx.x;
  int segB = segOff[s], segE = segOff[s+1];
  int cnt = segE - segB;
  int tiles = (cnt + 63) >> 6;

  // stage this species' weights once — FULL coverage:
  // W1T: 256 thr x 32 elems = 8192 = 64x128; W2T: 256 thr x 16 = 4096 = 64x64
  {
    int r = tid >> 2, q = tid & 3;
    const uint4* sp1 = (const uint4*)(w1t + (size_t)(s*64 + r)*128 + q*32);
    uint4 a0 = sp1[0], a1 = sp1[1], a2 = sp1[2], a3 = sp1[3];
    const uint4* sp2 = (const uint4*)(w2t + (size_t)(s*64 + r)*64 + q*16);
    uint4 c0 = sp2[0], c1 = sp2[1];
    uint4* d1 = (uint4*)(sW1 + r*136 + q*32);
    d1[0]=a0; d1[1]=a1; d1[2]=a2; d1[3]=a3;
    uint4* d2 = (uint4*)(sW2 + r*72 + q*16);
    d2[0]=c0; d2[1]=c1;
  }
  if (tid < 64)        sB1[tid]       = b1[s*64 + tid];
  else if (tid < 128)  sB2[tid-64]    = b2[s*64 + tid-64];
  else if (tid < 192)  sW3s[tid-128]  = W3[s*64 + tid-128];
  __syncthreads();

  int lane = tid & 63, wv = tid >> 6;
  int cc = lane & 15, quad = lane >> 4;

  // hoist all B-fragments + per-lane epilogue constants into registers
  v8bf bw1[4][4], bw2[4][2];
  float rb1[4], rb2[4], rw3[4];
  #pragma unroll
  for (int nt = 0; nt < 4; ++nt){
    #pragma unroll
    for (int kk = 0; kk < 4; ++kk)
      bw1[nt][kk] = *(const v8bf*)(sW1 + (nt*16+cc)*136 + kk*32 + quad*8);
    #pragma unroll
    for (int kk = 0; kk < 2; ++kk)
      bw2[nt][kk] = *(const v8bf*)(sW2 + (nt*16+cc)*72 + kk*32 + quad*8);
    rb1[nt] = sB1[nt*16+cc];
    rb2[nt] = sB2[nt*16+cc];
    rw3[nt] = sW3s[nt*16+cc];
  }
  float b3v = b3[s];
  u16* myH = sH[wv];

  if (tiles <= 0) return;

  // gather index for a tile (clamped so prefetch overruns stay in-bounds)
  auto idxLoad = [&](int t) -> int {
    int tc = t < tiles-1 ? t : tiles-1;
    int p = segB + tc*64 + wv*16 + cc;
    if (p > segE-1) p = segE-1;
    return sorted[p];
  };
  auto featLoad = [&](int ri, float4 (&f)[8]){
    const float4* fp = (const float4*)(feats + (size_t)ri*128 + quad*8);
    #pragma unroll
    for (int kk = 0; kk < 4; ++kk){ f[kk*2] = fp[kk*8]; f[kk*2+1] = fp[kk*8+1]; }
  };
  auto compute = [&](int t, const float4 (&f)[8], int ri){
    // layer 1
    v4f acc[4];
    #pragma unroll
    for (int nt = 0; nt < 4; ++nt) acc[nt] = (v4f){0.f,0.f,0.f,0.f};
    #pragma unroll
    for (int kk = 0; kk < 4; ++kk){
      union { v8bf v; unsigned u[4]; } A;
      A.u[0] = pack2bf(f[kk*2].x,   f[kk*2].y);
      A.u[1] = pack2bf(f[kk*2].z,   f[kk*2].w);
      A.u[2] = pack2bf(f[kk*2+1].x, f[kk*2+1].y);
      A.u[3] = pack2bf(f[kk*2+1].z, f[kk*2+1].w);
      #pragma unroll
      for (int nt = 0; nt < 4; ++nt)
        acc[nt] = __builtin_amdgcn_mfma_f32_16x16x32_bf16(A.v, bw1[nt][kk], acc[nt], 0, 0, 0);
    }
    // h1 = tanh(acc+b1) -> per-wave LDS scratch (C-layout -> A-layout)
    #pragma unroll
    for (int nt = 0; nt < 4; ++nt){
      #pragma unroll
      for (int r = 0; r < 4; ++r)
        myH[(quad*4+r)*72 + nt*16+cc] = h2bf(fast_tanh(acc[nt][r] + rb1[nt]));
    }
    // layer 2 (intra-wave LDS dep; compiler emits lgkmcnt wait, no barrier)
    v4f acc2[4];
    #pragma unroll
    for (int nt = 0; nt < 4; ++nt) acc2[nt] = (v4f){0.f,0.f,0.f,0.f};
    #pragma unroll
    for (int kk = 0; kk < 2; ++kk){
      v8bf hA = *(const v8bf*)(myH + cc*72 + kk*32 + quad*8);
      #pragma unroll
      for (int nt = 0; nt < 4; ++nt)
        acc2[nt] = __builtin_amdgcn_mfma_f32_16x16x32_bf16(hA, bw2[nt][kk], acc2[nt], 0, 0, 0);
    }
    // layer 3: fp32 dot + 16-lane reduce
    float p[4] = {0.f,0.f,0.f,0.f};
    #pragma unroll
    for (int nt = 0; nt < 4; ++nt){
      #pragma unroll
      for (int r = 0; r < 4; ++r)
        p[r] += fast_tanh(acc2[nt][r] + rb2[nt]) * rw3[nt];
    }
    #pragma unroll
    for (int off = 8; off >= 1; off >>= 1){
      #pragma unroll
      for (int r = 0; r < 4; ++r) p[r] += __shfl_xor(p[r], off, 64);
    }
    // fetch original atom ids for this lane's C-rows via shuffle (convergent)
    int rid[4];
    #pragma unroll
    for (int r = 0; r < 4; ++r) rid[r] = __shfl(ri, quad*4 + r, 64);
    if (cc == 0){
      int atomBase = t*64 + wv*16;
      #pragma unroll
      for (int r = 0; r < 4; ++r){
        int ap = atomBase + quad*4 + r;
        if (ap < cnt) out[rid[r]] = p[r] + b3v;
      }
    }
  };

  // 2-deep software pipeline: idx 2 tiles ahead, feats 1 tile ahead
  int t0 = bs;
  int riA = idxLoad(t0);
  int riB = idxLoad(t0 + BPS);
  float4 fA[8];
  featLoad(riA, fA);
  for (int t = t0; t < tiles; t += BPS){
    int riC = idxLoad(t + 2*BPS);
    float4 fB[8];
    featLoad(riB, fB);
    compute(t, fA, riA);
    riA = riB; riB = riC;
    #pragma unroll
    for (int i = 0; i < 8; ++i) fA[i] = fB[i];
  }
}

extern "C" void kernel_launch(void* const* d_in, const int* in_sizes, int n_in,
                              void* d_out, int out_size, void* d_ws, size_t ws_size,
                              hipStream_t stream){
  const float* feats  = (const float*)d_in[0];
  const int*   species= (const int*)d_in[1];
  const float* W1 = (const float*)d_in[2];
  const float* b1 = (const float*)d_in[3];
  const float* W2 = (const float*)d_in[4];
  const float* b2 = (const float*)d_in[5];
  const float* W3 = (const float*)d_in[6];
  const float* b3 = (const float*)d_in[7];
  float* out = (float*)d_out;
  int n = in_sizes[1];

  char* ws = (char*)d_ws;
  int* counts2  = (int*)ws;              // 256 ints
  int* cursors2 = (int*)(ws + 1024);     // 256 ints
  int* segOff   = (int*)(ws + 2048);     // 5 ints
  int* sorted   = (int*)(ws + 4096);     // n ints
  size_t sortedBytes = ((size_t)n*4 + 15) & ~(size_t)15;
  u16* w1t = (u16*)(ws + 4096 + sortedBytes);   // 4*64*128 bf16
  u16* w2t = w1t + NSP*64*128;                  // 4*64*64 bf16

  int nb = (n + 255) / 256;
  init_k<<<1, 256, 0, stream>>>(counts2);
  hist_k<<<nb, 256, 0, stream>>>(species, n, counts2);
  wconv_k<<<(NSP*128*64 + 255)/256, 256, 0, stream>>>(W1, W2, w1t, w2t);
  scan_k<<<1, 256, 0, stream>>>(counts2, cursors2, segOff);
  scatter_k<<<nb, 256, 0, stream>>>(species, n, cursors2, sorted);
  mlp2_k<<<NSP*BPS, 256, 0, stream>>>(feats, b1, b2, W3, b3, segOff, sorted, w1t, w2t, out);
}